// Round 1
// baseline (789.660 us; speedup 1.0000x reference)
//
#include <hip/hip_runtime.h>
#include <hip/hip_bf16.h>
#include <math.h>

typedef __bf16 bf16;
typedef __bf16 bf16x8 __attribute__((ext_vector_type(8)));
typedef float  f32x4  __attribute__((ext_vector_type(4)));

#define B_   8
#define T_   1024
#define H_   1024
#define MTOK (B_ * T_)   // 8192 token rows

static __device__ __forceinline__ float gelu_f(float x) {
    return 0.5f * x * (1.0f + erff(x * 0.70710678118654752f));
}

// ---------------------------------------------------------------------------
// Weight prep: fp32 (K x N) -> bf16 (N x K)  (transpose + cast)
// ---------------------------------------------------------------------------
__global__ __launch_bounds__(256)
void transpose_cast_k(const float* __restrict__ in, bf16* __restrict__ out,
                      int Kd, int Nd)
{
    __shared__ float tile[32][33];
    int n0 = blockIdx.x * 32;
    int k0 = blockIdx.y * 32;
    int tx = threadIdx.x & 31, ty = threadIdx.x >> 5;   // 32 x 8
#pragma unroll
    for (int i = 0; i < 32; i += 8)
        tile[ty + i][tx] = in[(size_t)(k0 + ty + i) * Nd + n0 + tx];
    __syncthreads();
#pragma unroll
    for (int i = 0; i < 32; i += 8)
        out[(size_t)(n0 + ty + i) * Kd + k0 + tx] = (bf16)tile[tx][ty + i];
}

// fp32 -> bf16 elementwise (pw_w is already [o][c] = [n][k])
__global__ __launch_bounds__(256)
void cast_k(const float* __restrict__ in, bf16* __restrict__ out)
{
    int i = blockIdx.x * 256 + threadIdx.x;
    float4 v = ((const float4*)in)[i];
    bf16* o = out + (size_t)i * 4;
    o[0] = (bf16)v.x; o[1] = (bf16)v.y; o[2] = (bf16)v.z; o[3] = (bf16)v.w;
}

// ---------------------------------------------------------------------------
// LayerNorm over H=1024, fp32 in -> bf16 out. One block per row.
// ---------------------------------------------------------------------------
__global__ __launch_bounds__(256)
void ln_k(const float* __restrict__ x, const float* __restrict__ g,
          const float* __restrict__ b, bf16* __restrict__ out)
{
    int row = blockIdx.x;
    float4 v = ((const float4*)(x + (size_t)row * H_))[threadIdx.x];
    float s  = v.x + v.y + v.z + v.w;
    float s2 = v.x * v.x + v.y * v.y + v.z * v.z + v.w * v.w;
#pragma unroll
    for (int off = 32; off > 0; off >>= 1) {
        s  += __shfl_down(s, off);
        s2 += __shfl_down(s2, off);
    }
    __shared__ float red[8];
    int wave = threadIdx.x >> 6, lane = threadIdx.x & 63;
    if (lane == 0) { red[wave] = s; red[wave + 4] = s2; }
    __syncthreads();
    s  = red[0] + red[1] + red[2] + red[3];
    s2 = red[4] + red[5] + red[6] + red[7];
    float mean = s * (1.0f / H_);
    float var  = s2 * (1.0f / H_) - mean * mean;
    float rstd = rsqrtf(var + 1e-5f);
    int c = threadIdx.x * 4;
    float4 gv = *(const float4*)(g + c);
    float4 bv = *(const float4*)(b + c);
    bf16* o = out + (size_t)row * H_ + c;
    o[0] = (bf16)((v.x - mean) * rstd * gv.x + bv.x);
    o[1] = (bf16)((v.y - mean) * rstd * gv.y + bv.y);
    o[2] = (bf16)((v.z - mean) * rstd * gv.z + bv.z);
    o[3] = (bf16)((v.w - mean) * rstd * gv.w + bv.w);
}

// ---------------------------------------------------------------------------
// Causal depthwise conv (k=3) + bias + exact GELU. Token-major, bf16->bf16.
// ---------------------------------------------------------------------------
__global__ __launch_bounds__(256)
void dwconv_k(const bf16* __restrict__ cl, const float* __restrict__ kw,
              const float* __restrict__ kb, bf16* __restrict__ out)
{
    size_t idx = (size_t)blockIdx.x * 256 + threadIdx.x;
    int ch = (int)(idx & (H_ - 1));
    int t  = (int)((idx >> 10) & (T_ - 1));
    float acc = kb[ch];
    float w0 = kw[ch * 3 + 0], w1 = kw[ch * 3 + 1], w2 = kw[ch * 3 + 2];
    acc += (float)cl[idx] * w2;
    if (t >= 1) acc += (float)cl[idx - H_] * w1;
    if (t >= 2) acc += (float)cl[idx - 2 * H_] * w0;
    out[idx] = (bf16)gelu_f(acc);
}

// ---------------------------------------------------------------------------
// bf16 MFMA GEMM: C(MxN) = A(MxK) @ W(KxN) with W given transposed (WT: NxK).
// 128x128 tile, BK=32, 256 threads (4 waves, 2x2 of 64x64; 4x4 MFMA tiles).
// EPI: 0 = gelu(acc+bias)->bf16, 1 = (acc+bias)->bf16,
//      2 = acc+bias+res -> fp32 (res may alias out), 3 = res + 0.5*(acc+bias) -> fp32
// ---------------------------------------------------------------------------
#define BM 128
#define BN 128
#define BK 32
#define LDK 40   // pad: 80B row stride keeps 16B alignment, 2-way-free banks

template<int EPI>
__global__ __launch_bounds__(256)
void gemm_k(const bf16* __restrict__ A, const bf16* __restrict__ WT,
            const float* __restrict__ bias, const float* __restrict__ res,
            float* __restrict__ outF, bf16* __restrict__ outB,
            int N, int K)
{
    __shared__ bf16 As[BM * LDK];
    __shared__ bf16 Bs[BN * LDK];
    const int tid  = threadIdx.x;
    const int wave = tid >> 6;
    const int lane = tid & 63;
    const int quad = lane >> 4;
    const int lr   = lane & 15;
    const int bm = blockIdx.x * BM;
    const int bn = blockIdx.y * BN;
    const int wm = (wave & 1) * 64;
    const int wn = (wave >> 1) * 64;

    f32x4 acc[4][4];
#pragma unroll
    for (int mi = 0; mi < 4; mi++)
#pragma unroll
        for (int ni = 0; ni < 4; ni++)
#pragma unroll
            for (int r = 0; r < 4; r++) acc[mi][ni][r] = 0.f;

    for (int k0 = 0; k0 < K; k0 += BK) {
#pragma unroll
        for (int i = 0; i < 2; i++) {
            int c = tid + i * 256;          // 512 chunks: 128 rows x 4 chunks of 8
            int row = c >> 2;
            int col = (c & 3) << 3;
            *(bf16x8*)(&As[row * LDK + col]) =
                *(const bf16x8*)(&A[(size_t)(bm + row) * K + k0 + col]);
            *(bf16x8*)(&Bs[row * LDK + col]) =
                *(const bf16x8*)(&WT[(size_t)(bn + row) * K + k0 + col]);
        }
        __syncthreads();
        bf16x8 af[4], bfr[4];
#pragma unroll
        for (int mi = 0; mi < 4; mi++)
            af[mi] = *(const bf16x8*)(&As[(wm + mi * 16 + lr) * LDK + quad * 8]);
#pragma unroll
        for (int ni = 0; ni < 4; ni++)
            bfr[ni] = *(const bf16x8*)(&Bs[(wn + ni * 16 + lr) * LDK + quad * 8]);
#pragma unroll
        for (int mi = 0; mi < 4; mi++)
#pragma unroll
            for (int ni = 0; ni < 4; ni++)
                acc[mi][ni] = __builtin_amdgcn_mfma_f32_16x16x32_bf16(
                    af[mi], bfr[ni], acc[mi][ni], 0, 0, 0);
        __syncthreads();
    }

    // epilogue — C/D layout: col = lane&15, row = quad*4 + reg  [m89-verified]
#pragma unroll
    for (int mi = 0; mi < 4; mi++) {
#pragma unroll
        for (int ni = 0; ni < 4; ni++) {
            int col = bn + wn + ni * 16 + lr;
            float bv = bias[col];
#pragma unroll
            for (int r = 0; r < 4; r++) {
                int row = bm + wm + mi * 16 + quad * 4 + r;
                size_t idx = (size_t)row * N + col;
                float v = acc[mi][ni][r] + bv;
                if (EPI == 0)      outB[idx] = (bf16)gelu_f(v);
                else if (EPI == 1) outB[idx] = (bf16)v;
                else if (EPI == 2) outF[idx] = v + res[idx];
                else               outF[idx] = res[idx] + 0.5f * v;
            }
        }
    }
}

// ---------------------------------------------------------------------------
// Flash attention: grid (16 q-tiles, B*NH). Block = 4 waves; wave owns a
// 16-row q stripe, iterates 64-wide k tiles with online softmax.
// qkv: row-major [b*T+t][3072], q at +0, k at +1024, v at +2048 (per head *64).
// ---------------------------------------------------------------------------
#define ASTR 72   // 144B rows: 16B aligned, 2-way-free banks

__global__ __launch_bounds__(256)
void attn_k(const bf16* __restrict__ qkv, bf16* __restrict__ o)
{
    const int qt = blockIdx.x;          // 0..15
    const int bh = blockIdx.y;          // b*16 + h
    const int b = bh >> 4, h = bh & 15;
    const int tid  = threadIdx.x;
    const int wave = tid >> 6, lane = tid & 63;
    const int quad = lane >> 4, lr = lane & 15;
    const int wq = wave * 16;

    __shared__ bf16 Qs[64 * ASTR];
    __shared__ bf16 Ks[64 * ASTR];
    __shared__ bf16 Vt[64 * ASTR];          // transposed: [hd][s]
    __shared__ bf16 Ps[4][16 * ASTR];       // per-wave P stripe [q][s]

    const size_t base = (size_t)b * T_ * 3072;

    // stage Q tile (64 x 64)
#pragma unroll
    for (int i = 0; i < 2; i++) {
        int c = tid + i * 256;
        int row = c >> 3, ch = (c & 7) << 3;
        *(bf16x8*)(&Qs[row * ASTR + ch]) =
            *(const bf16x8*)(&qkv[base + (size_t)(qt * 64 + row) * 3072 + h * 64 + ch]);
    }
    __syncthreads();
    bf16x8 qf[2];
    qf[0] = *(const bf16x8*)(&Qs[(wq + lr) * ASTR + quad * 8]);
    qf[1] = *(const bf16x8*)(&Qs[(wq + lr) * ASTR + 32 + quad * 8]);

    f32x4 oacc[4];
    float m_run[4], l_run[4];
#pragma unroll
    for (int ni = 0; ni < 4; ni++)
#pragma unroll
        for (int r = 0; r < 4; r++) oacc[ni][r] = 0.f;
#pragma unroll
    for (int r = 0; r < 4; r++) { m_run[r] = -INFINITY; l_run[r] = 0.f; }

    for (int kt = 0; kt <= qt; kt++) {
        __syncthreads();   // all waves done with previous K/V
#pragma unroll
        for (int i = 0; i < 2; i++) {
            int c = tid + i * 256;
            int row = c >> 3, ch = (c & 7) << 3;
            *(bf16x8*)(&Ks[row * ASTR + ch]) =
                *(const bf16x8*)(&qkv[base + (size_t)(kt * 64 + row) * 3072 + 1024 + h * 64 + ch]);
            bf16x8 vv =
                *(const bf16x8*)(&qkv[base + (size_t)(kt * 64 + row) * 3072 + 2048 + h * 64 + ch]);
#pragma unroll
            for (int j = 0; j < 8; j++)
                Vt[(ch + j) * ASTR + row] = vv[j];
        }
        __syncthreads();

        // S = Q @ K^T  (per wave: 16 q x 64 s)
        f32x4 sv[4];
#pragma unroll
        for (int ni = 0; ni < 4; ni++) {
            bf16x8 kf0 = *(const bf16x8*)(&Ks[(ni * 16 + lr) * ASTR + quad * 8]);
            bf16x8 kf1 = *(const bf16x8*)(&Ks[(ni * 16 + lr) * ASTR + 32 + quad * 8]);
            f32x4 t;
#pragma unroll
            for (int r = 0; r < 4; r++) t[r] = 0.f;
            t = __builtin_amdgcn_mfma_f32_16x16x32_bf16(qf[0], kf0, t, 0, 0, 0);
            t = __builtin_amdgcn_mfma_f32_16x16x32_bf16(qf[1], kf1, t, 0, 0, 0);
            sv[ni] = t;
        }

        // scale + causal mask + online softmax (rows = quad*4+r, cols = ni*16+lr)
        const int gq_base = qt * 64 + wq + quad * 4;
        const int gs_base = kt * 64 + lr;
        float rmax[4];
#pragma unroll
        for (int r = 0; r < 4; r++) rmax[r] = -INFINITY;
#pragma unroll
        for (int ni = 0; ni < 4; ni++)
#pragma unroll
            for (int r = 0; r < 4; r++) {
                float xv = sv[ni][r] * 0.125f;
                if (gs_base + ni * 16 > gq_base + r) xv = -INFINITY;
                sv[ni][r] = xv;
                rmax[r] = fmaxf(rmax[r], xv);
            }
#pragma unroll
        for (int off = 1; off < 16; off <<= 1)
#pragma unroll
            for (int r = 0; r < 4; r++)
                rmax[r] = fmaxf(rmax[r], __shfl_xor(rmax[r], off));

        float alpha[4], rsum[4];
#pragma unroll
        for (int r = 0; r < 4; r++) {
            float mn = fmaxf(m_run[r], rmax[r]);
            alpha[r] = __expf(m_run[r] - mn);   // first tile: exp(-inf)=0
            m_run[r] = mn;
            rsum[r] = 0.f;
        }
#pragma unroll
        for (int ni = 0; ni < 4; ni++)
#pragma unroll
            for (int r = 0; r < 4; r++) {
                float p = __expf(sv[ni][r] - m_run[r]);  // masked -> exp(-inf)=0
                rsum[r] += p;
                Ps[wave][(quad * 4 + r) * ASTR + ni * 16 + lr] = (bf16)p;
            }
#pragma unroll
        for (int off = 1; off < 16; off <<= 1)
#pragma unroll
            for (int r = 0; r < 4; r++)
                rsum[r] += __shfl_xor(rsum[r], off);
#pragma unroll
        for (int r = 0; r < 4; r++)
            l_run[r] = l_run[r] * alpha[r] + rsum[r];
#pragma unroll
        for (int ni = 0; ni < 4; ni++)
#pragma unroll
            for (int r = 0; r < 4; r++)
                oacc[ni][r] *= alpha[r];

        // O += P @ V   (P via LDS round-trip into A-layout; Vt is B-layout)
        bf16x8 pf0 = *(const bf16x8*)(&Ps[wave][lr * ASTR + quad * 8]);
        bf16x8 pf1 = *(const bf16x8*)(&Ps[wave][lr * ASTR + 32 + quad * 8]);
#pragma unroll
        for (int ni = 0; ni < 4; ni++) {
            bf16x8 vf0 = *(const bf16x8*)(&Vt[(ni * 16 + lr) * ASTR + quad * 8]);
            bf16x8 vf1 = *(const bf16x8*)(&Vt[(ni * 16 + lr) * ASTR + 32 + quad * 8]);
            oacc[ni] = __builtin_amdgcn_mfma_f32_16x16x32_bf16(pf0, vf0, oacc[ni], 0, 0, 0);
            oacc[ni] = __builtin_amdgcn_mfma_f32_16x16x32_bf16(pf1, vf1, oacc[ni], 0, 0, 0);
        }
    }

    // normalize + write o[b, q, h*64 + hd] as bf16
#pragma unroll
    for (int r = 0; r < 4; r++) {
        float inv = 1.0f / l_run[r];
        int gq = qt * 64 + wq + quad * 4 + r;
#pragma unroll
        for (int ni = 0; ni < 4; ni++)
            o[((size_t)(b * T_ + gq)) * H_ + h * 64 + ni * 16 + lr] =
                (bf16)(oacc[ni][r] * inv);
    }
}

// ---------------------------------------------------------------------------
extern "C" void kernel_launch(void* const* d_in, const int* in_sizes, int n_in,
                              void* d_out, int out_size, void* d_ws, size_t ws_size,
                              hipStream_t stream)
{
    const float* x_in  = (const float*)d_in[0];
    const float* ln1_g = (const float*)d_in[1];
    const float* ln1_b = (const float*)d_in[2];
    const float* f1w1  = (const float*)d_in[3];
    const float* f1b1  = (const float*)d_in[4];
    const float* f1w2  = (const float*)d_in[5];
    const float* f1b2  = (const float*)d_in[6];
    const float* an_g  = (const float*)d_in[7];
    const float* an_b  = (const float*)d_in[8];
    const float* qkv_w = (const float*)d_in[9];
    const float* qkv_b = (const float*)d_in[10];
    const float* out_w = (const float*)d_in[11];
    const float* out_b = (const float*)d_in[12];
    const float* cn_g  = (const float*)d_in[13];
    const float* cn_b  = (const float*)d_in[14];
    const float* dw_k  = (const float*)d_in[15];
    const float* dw_b  = (const float*)d_in[16];
    const float* pw_w  = (const float*)d_in[17];
    const float* pw_b  = (const float*)d_in[18];
    const float* ln2_g = (const float*)d_in[19];
    const float* ln2_b = (const float*)d_in[20];
    const float* f2w1  = (const float*)d_in[21];
    const float* f2b1  = (const float*)d_in[22];
    const float* f2w2  = (const float*)d_in[23];
    const float* f2b2  = (const float*)d_in[24];
    float* outp = (float*)d_out;

    char* ws = (char*)d_ws;
    size_t off = 0;
    auto alloc = [&](size_t bytes) {
        char* p = ws + off;
        off += (bytes + 255) & ~(size_t)255;
        return p;
    };
    bf16* w1T_1 = (bf16*)alloc(2048ULL * 1024 * 2);
    bf16* w2T_1 = (bf16*)alloc(1024ULL * 2048 * 2);
    bf16* qkvT  = (bf16*)alloc(3072ULL * 1024 * 2);
    bf16* outT  = (bf16*)alloc(1024ULL * 1024 * 2);
    bf16* pwB   = (bf16*)alloc(1024ULL * 1024 * 2);
    bf16* w1T_2 = (bf16*)alloc(2048ULL * 1024 * 2);
    bf16* w2T_2 = (bf16*)alloc(1024ULL * 2048 * 2);
    bf16* bufa  = (bf16*)alloc((size_t)MTOK * 1024 * 2);   // LN outs / attn out
    bf16* gbuf  = (bf16*)alloc((size_t)MTOK * 1024 * 2);   // conv-gelu out
    bf16* hid   = (bf16*)alloc((size_t)MTOK * 3072 * 2);   // ffn hidden / qkv
    float* xw   = (float*)alloc((size_t)MTOK * 1024 * 4);  // running residual x

    // ---- weight prep (bf16, B pre-transposed to [n][k]) ----
    transpose_cast_k<<<dim3(64, 32), 256, 0, stream>>>(f1w1, w1T_1, 1024, 2048);
    transpose_cast_k<<<dim3(32, 64), 256, 0, stream>>>(f1w2, w2T_1, 2048, 1024);
    transpose_cast_k<<<dim3(96, 32), 256, 0, stream>>>(qkv_w, qkvT, 1024, 3072);
    transpose_cast_k<<<dim3(32, 32), 256, 0, stream>>>(out_w, outT, 1024, 1024);
    transpose_cast_k<<<dim3(64, 32), 256, 0, stream>>>(f2w1, w1T_2, 1024, 2048);
    transpose_cast_k<<<dim3(32, 64), 256, 0, stream>>>(f2w2, w2T_2, 2048, 1024);
    cast_k<<<1024, 256, 0, stream>>>(pw_w, pwB);

    // ---- FFN1 (x += 0.5 * ffn(ln1(x))) ----
    ln_k<<<MTOK, 256, 0, stream>>>(x_in, ln1_g, ln1_b, bufa);
    gemm_k<0><<<dim3(64, 16), 256, 0, stream>>>(bufa, w1T_1, f1b1, nullptr, nullptr, hid, 2048, 1024);
    gemm_k<3><<<dim3(64, 8), 256, 0, stream>>>(hid, w2T_1, f1b2, x_in, xw, nullptr, 1024, 2048);

    // ---- attention ----
    ln_k<<<MTOK, 256, 0, stream>>>(xw, an_g, an_b, bufa);
    gemm_k<1><<<dim3(64, 24), 256, 0, stream>>>(bufa, qkvT, qkv_b, nullptr, nullptr, hid, 3072, 1024);
    attn_k<<<dim3(16, 128), 256, 0, stream>>>(hid, bufa);
    gemm_k<2><<<dim3(64, 8), 256, 0, stream>>>(bufa, outT, out_b, xw, xw, nullptr, 1024, 1024);

    // ---- conv module ----
    ln_k<<<MTOK, 256, 0, stream>>>(xw, cn_g, cn_b, bufa);
    dwconv_k<<<MTOK * 1024 / 256, 256, 0, stream>>>(bufa, dw_k, dw_b, gbuf);
    gemm_k<2><<<dim3(64, 8), 256, 0, stream>>>(gbuf, pwB, pw_b, xw, xw, nullptr, 1024, 1024);

    // ---- FFN2 ----
    ln_k<<<MTOK, 256, 0, stream>>>(xw, ln2_g, ln2_b, bufa);
    gemm_k<0><<<dim3(64, 16), 256, 0, stream>>>(bufa, w1T_2, f2b1, nullptr, nullptr, hid, 2048, 1024);
    gemm_k<3><<<dim3(64, 8), 256, 0, stream>>>(hid, w2T_2, f2b2, xw, outp, nullptr, 1024, 2048);
}

// Round 2
// 743.684 us; speedup vs baseline: 1.0618x; 1.0618x over previous
//
#include <hip/hip_runtime.h>
#include <hip/hip_bf16.h>
#include <math.h>

typedef __bf16 bf16;
typedef __bf16 bf16x8 __attribute__((ext_vector_type(8)));
typedef float  f32x4  __attribute__((ext_vector_type(4)));

#define B_   8
#define T_   1024
#define H_   1024
#define MTOK (B_ * T_)   // 8192 token rows

static __device__ __forceinline__ float gelu_f(float x) {
    return 0.5f * x * (1.0f + erff(x * 0.70710678118654752f));
}

// async global->LDS, 16B per lane. LDS dest = wave-uniform base + lane*16.
static __device__ __forceinline__ void async16(const bf16* g, bf16* l) {
    __builtin_amdgcn_global_load_lds(
        (const __attribute__((address_space(1))) void*)g,
        (__attribute__((address_space(3))) void*)l, 16, 0, 0);
}

// ---------------------------------------------------------------------------
// Weight prep: fp32 (K x N) -> bf16 (N x K)  (transpose + cast)
// ---------------------------------------------------------------------------
__global__ __launch_bounds__(256)
void transpose_cast_k(const float* __restrict__ in, bf16* __restrict__ out,
                      int Kd, int Nd)
{
    __shared__ float tile[32][33];
    int n0 = blockIdx.x * 32;
    int k0 = blockIdx.y * 32;
    int tx = threadIdx.x & 31, ty = threadIdx.x >> 5;   // 32 x 8
#pragma unroll
    for (int i = 0; i < 32; i += 8)
        tile[ty + i][tx] = in[(size_t)(k0 + ty + i) * Nd + n0 + tx];
    __syncthreads();
#pragma unroll
    for (int i = 0; i < 32; i += 8)
        out[(size_t)(n0 + ty + i) * Kd + k0 + tx] = (bf16)tile[tx][ty + i];
}

// fp32 -> bf16 elementwise (pw_w is already [o][c] = [n][k])
__global__ __launch_bounds__(256)
void cast_k(const float* __restrict__ in, bf16* __restrict__ out)
{
    int i = blockIdx.x * 256 + threadIdx.x;
    float4 v = ((const float4*)in)[i];
    bf16* o = out + (size_t)i * 4;
    o[0] = (bf16)v.x; o[1] = (bf16)v.y; o[2] = (bf16)v.z; o[3] = (bf16)v.w;
}

// ---------------------------------------------------------------------------
// V transpose: qkv[b*T+t][2048 + h*64 + hd] -> vt[(bh*64 + hd)*T + t]
// ---------------------------------------------------------------------------
__global__ __launch_bounds__(256)
void transpose_v_k(const bf16* __restrict__ qkv, bf16* __restrict__ vt)
{
    __shared__ bf16 tile[64][72];
    const int t0 = blockIdx.x * 64;
    const int bh = blockIdx.y;
    const int b = bh >> 4, h = bh & 15;
    const int tid = threadIdx.x;
#pragma unroll
    for (int i = 0; i < 2; i++) {
        int c = tid + i * 256;
        int row = c >> 3, ch = (c & 7) << 3;
        *(bf16x8*)(&tile[row][ch]) =
            *(const bf16x8*)(&qkv[(size_t)(b * T_ + t0 + row) * 3072 + 2048 + h * 64 + ch]);
    }
    __syncthreads();
#pragma unroll
    for (int i = 0; i < 2; i++) {
        int c = tid + i * 256;
        int hd = c >> 3, tc = (c & 7) << 3;
        bf16x8 v;
#pragma unroll
        for (int j = 0; j < 8; j++) v[j] = tile[tc + j][hd];
        *(bf16x8*)(&vt[((size_t)bh * 64 + hd) * T_ + t0 + tc]) = v;
    }
}

// ---------------------------------------------------------------------------
// LayerNorm over H=1024, fp32 in -> bf16 out. One block per row.
// ---------------------------------------------------------------------------
__global__ __launch_bounds__(256)
void ln_k(const float* __restrict__ x, const float* __restrict__ g,
          const float* __restrict__ b, bf16* __restrict__ out)
{
    int row = blockIdx.x;
    float4 v = ((const float4*)(x + (size_t)row * H_))[threadIdx.x];
    float s  = v.x + v.y + v.z + v.w;
    float s2 = v.x * v.x + v.y * v.y + v.z * v.z + v.w * v.w;
#pragma unroll
    for (int off = 32; off > 0; off >>= 1) {
        s  += __shfl_down(s, off);
        s2 += __shfl_down(s2, off);
    }
    __shared__ float red[8];
    int wave = threadIdx.x >> 6, lane = threadIdx.x & 63;
    if (lane == 0) { red[wave] = s; red[wave + 4] = s2; }
    __syncthreads();
    s  = red[0] + red[1] + red[2] + red[3];
    s2 = red[4] + red[5] + red[6] + red[7];
    float mean = s * (1.0f / H_);
    float var  = s2 * (1.0f / H_) - mean * mean;
    float rstd = rsqrtf(var + 1e-5f);
    int c = threadIdx.x * 4;
    float4 gv = *(const float4*)(g + c);
    float4 bv = *(const float4*)(b + c);
    bf16* o = out + (size_t)row * H_ + c;
    o[0] = (bf16)((v.x - mean) * rstd * gv.x + bv.x);
    o[1] = (bf16)((v.y - mean) * rstd * gv.y + bv.y);
    o[2] = (bf16)((v.z - mean) * rstd * gv.z + bv.z);
    o[3] = (bf16)((v.w - mean) * rstd * gv.w + bv.w);
}

// ---------------------------------------------------------------------------
// Causal depthwise conv (k=3) + bias + exact GELU. Token-major, bf16->bf16.
// ---------------------------------------------------------------------------
__global__ __launch_bounds__(256)
void dwconv_k(const bf16* __restrict__ cl, const float* __restrict__ kw,
              const float* __restrict__ kb, bf16* __restrict__ out)
{
    size_t idx = (size_t)blockIdx.x * 256 + threadIdx.x;
    int ch = (int)(idx & (H_ - 1));
    int t  = (int)((idx >> 10) & (T_ - 1));
    float acc = kb[ch];
    float w0 = kw[ch * 3 + 0], w1 = kw[ch * 3 + 1], w2 = kw[ch * 3 + 2];
    acc += (float)cl[idx] * w2;
    if (t >= 1) acc += (float)cl[idx - H_] * w1;
    if (t >= 2) acc += (float)cl[idx - 2 * H_] * w0;
    out[idx] = (bf16)gelu_f(acc);
}

// ---------------------------------------------------------------------------
// bf16 MFMA GEMM (m97 structure): C(MxN) = A(MxK) @ WT(NxK)^T.
// 128x128 tile, BK=32, 256 threads; global_load_lds width-16 staging into
// unpadded LDS [128][32].
// EPI: 0 = gelu(acc+bias)->bf16, 1 = (acc+bias)->bf16,
//      2 = acc+bias+res -> fp32 (res may alias out), 3 = res + 0.5*(acc+bias) -> fp32
// ---------------------------------------------------------------------------
#define BM 128
#define BN 128
#define BK 32

template<int EPI>
__global__ __launch_bounds__(256)
void gemm_k(const bf16* __restrict__ A, const bf16* __restrict__ WT,
            const float* __restrict__ bias, const float* __restrict__ res,
            float* __restrict__ outF, bf16* __restrict__ outB,
            int N, int K)
{
    __shared__ bf16 As[BM * BK];
    __shared__ bf16 Bs[BN * BK];
    const int tid  = threadIdx.x;
    const int wave = tid >> 6;
    const int lane = tid & 63;
    const int quad = lane >> 4;
    const int lr   = lane & 15;
    const int bm = blockIdx.x * BM;
    const int bn = blockIdx.y * BN;
    const int wm = (wave & 1) * 64;
    const int wn = (wave >> 1) * 64;

    // staging geometry: chunk = 16 rows x 32 cols = 1024B; lane -> (row, col)
    const int crow = lane >> 2;          // 0..15
    const int ccol = (lane & 3) << 3;    // 0,8,16,24

    f32x4 acc[4][4];
#pragma unroll
    for (int mi = 0; mi < 4; mi++)
#pragma unroll
        for (int ni = 0; ni < 4; ni++)
#pragma unroll
            for (int r = 0; r < 4; r++) acc[mi][ni][r] = 0.f;

    for (int k0 = 0; k0 < K; k0 += BK) {
#pragma unroll
        for (int t = 0; t < 2; t++) {
            const int c = wave * 2 + t;            // chunk 0..7
            async16(&A[(size_t)(bm + c * 16 + crow) * K + k0 + ccol], &As[c * 512]);
            async16(&WT[(size_t)(bn + c * 16 + crow) * K + k0 + ccol], &Bs[c * 512]);
        }
        __syncthreads();
        bf16x8 af[4], bfr[4];
#pragma unroll
        for (int mi = 0; mi < 4; mi++)
            af[mi] = *(const bf16x8*)(&As[(wm + mi * 16 + lr) * BK + quad * 8]);
#pragma unroll
        for (int ni = 0; ni < 4; ni++)
            bfr[ni] = *(const bf16x8*)(&Bs[(wn + ni * 16 + lr) * BK + quad * 8]);
#pragma unroll
        for (int mi = 0; mi < 4; mi++)
#pragma unroll
            for (int ni = 0; ni < 4; ni++)
                acc[mi][ni] = __builtin_amdgcn_mfma_f32_16x16x32_bf16(
                    af[mi], bfr[ni], acc[mi][ni], 0, 0, 0);
        __syncthreads();
    }

    // epilogue — C/D layout: col = lane&15, row = quad*4 + reg  [m89-verified]
#pragma unroll
    for (int mi = 0; mi < 4; mi++) {
#pragma unroll
        for (int ni = 0; ni < 4; ni++) {
            int col = bn + wn + ni * 16 + lr;
            float bv = bias[col];
#pragma unroll
            for (int r = 0; r < 4; r++) {
                int row = bm + wm + mi * 16 + quad * 4 + r;
                size_t idx = (size_t)row * N + col;
                float v = acc[mi][ni][r] + bv;
                if (EPI == 0)      outB[idx] = (bf16)gelu_f(v);
                else if (EPI == 1) outB[idx] = (bf16)v;
                else if (EPI == 2) outF[idx] = v + res[idx];
                else               outF[idx] = res[idx] + 0.5f * v;
            }
        }
    }
}

// ---------------------------------------------------------------------------
// Flash attention: grid (16 q-tiles, B*NH). Block = 4 waves; wave owns a
// 16-row q stripe, iterates 64-wide k tiles with online softmax.
// qkv: row-major [b*T+t][3072], q at +0, k at +1024 (per head *64).
// vt:  [bh*64 + hd][t]  (pre-transposed V, B-operand-ready)
// ---------------------------------------------------------------------------
#define ASTR 72   // 144B rows: 16B aligned

__global__ __launch_bounds__(256)
void attn_k(const bf16* __restrict__ qkv, const bf16* __restrict__ vt,
            bf16* __restrict__ o)
{
    const int qt = blockIdx.x;          // 0..15
    const int bh = blockIdx.y;          // b*16 + h
    const int b = bh >> 4, h = bh & 15;
    const int tid  = threadIdx.x;
    const int wave = tid >> 6, lane = tid & 63;
    const int quad = lane >> 4, lr = lane & 15;
    const int wq = wave * 16;

    __shared__ bf16 Qs[64 * ASTR];
    __shared__ bf16 Ks[64 * ASTR];
    __shared__ bf16 Vts[64 * ASTR];         // [hd][s]
    __shared__ bf16 Ps[4][16 * ASTR];       // per-wave P stripe [q][s]

    const size_t base = (size_t)b * T_ * 3072;
    const size_t vtbase = (size_t)bh * 64 * T_;

    // stage Q tile (64 x 64)
#pragma unroll
    for (int i = 0; i < 2; i++) {
        int c = tid + i * 256;
        int row = c >> 3, ch = (c & 7) << 3;
        *(bf16x8*)(&Qs[row * ASTR + ch]) =
            *(const bf16x8*)(&qkv[base + (size_t)(qt * 64 + row) * 3072 + h * 64 + ch]);
    }
    __syncthreads();
    bf16x8 qf[2];
    qf[0] = *(const bf16x8*)(&Qs[(wq + lr) * ASTR + quad * 8]);
    qf[1] = *(const bf16x8*)(&Qs[(wq + lr) * ASTR + 32 + quad * 8]);

    f32x4 oacc[4];
    float m_run[4], l_run[4];
#pragma unroll
    for (int ni = 0; ni < 4; ni++)
#pragma unroll
        for (int r = 0; r < 4; r++) oacc[ni][r] = 0.f;
#pragma unroll
    for (int r = 0; r < 4; r++) { m_run[r] = -INFINITY; l_run[r] = 0.f; }

    for (int kt = 0; kt <= qt; kt++) {
        __syncthreads();   // all waves done with previous K/V
#pragma unroll
        for (int i = 0; i < 2; i++) {
            int c = tid + i * 256;
            int row = c >> 3, ch = (c & 7) << 3;
            *(bf16x8*)(&Ks[row * ASTR + ch]) =
                *(const bf16x8*)(&qkv[base + (size_t)(kt * 64 + row) * 3072 + 1024 + h * 64 + ch]);
            *(bf16x8*)(&Vts[row * ASTR + ch]) =
                *(const bf16x8*)(&vt[vtbase + (size_t)row * T_ + kt * 64 + ch]);
        }
        __syncthreads();

        // S = Q @ K^T  (per wave: 16 q x 64 s)
        f32x4 sv[4];
#pragma unroll
        for (int ni = 0; ni < 4; ni++) {
            bf16x8 kf0 = *(const bf16x8*)(&Ks[(ni * 16 + lr) * ASTR + quad * 8]);
            bf16x8 kf1 = *(const bf16x8*)(&Ks[(ni * 16 + lr) * ASTR + 32 + quad * 8]);
            f32x4 t;
#pragma unroll
            for (int r = 0; r < 4; r++) t[r] = 0.f;
            t = __builtin_amdgcn_mfma_f32_16x16x32_bf16(qf[0], kf0, t, 0, 0, 0);
            t = __builtin_amdgcn_mfma_f32_16x16x32_bf16(qf[1], kf1, t, 0, 0, 0);
            sv[ni] = t;
        }

        // scale + causal mask + online softmax (rows = quad*4+r, cols = ni*16+lr)
        const int gq_base = qt * 64 + wq + quad * 4;
        const int gs_base = kt * 64 + lr;
        float rmax[4];
#pragma unroll
        for (int r = 0; r < 4; r++) rmax[r] = -INFINITY;
#pragma unroll
        for (int ni = 0; ni < 4; ni++)
#pragma unroll
            for (int r = 0; r < 4; r++) {
                float xv = sv[ni][r] * 0.125f;
                if (gs_base + ni * 16 > gq_base + r) xv = -INFINITY;
                sv[ni][r] = xv;
                rmax[r] = fmaxf(rmax[r], xv);
            }
#pragma unroll
        for (int off = 1; off < 16; off <<= 1)
#pragma unroll
            for (int r = 0; r < 4; r++)
                rmax[r] = fmaxf(rmax[r], __shfl_xor(rmax[r], off));

        float alpha[4], rsum[4];
#pragma unroll
        for (int r = 0; r < 4; r++) {
            float mn = fmaxf(m_run[r], rmax[r]);
            alpha[r] = __expf(m_run[r] - mn);   // first tile: exp(-inf)=0
            m_run[r] = mn;
            rsum[r] = 0.f;
        }
#pragma unroll
        for (int ni = 0; ni < 4; ni++)
#pragma unroll
            for (int r = 0; r < 4; r++) {
                float p = __expf(sv[ni][r] - m_run[r]);  // masked -> exp(-inf)=0
                rsum[r] += p;
                Ps[wave][(quad * 4 + r) * ASTR + ni * 16 + lr] = (bf16)p;
            }
#pragma unroll
        for (int off = 1; off < 16; off <<= 1)
#pragma unroll
            for (int r = 0; r < 4; r++)
                rsum[r] += __shfl_xor(rsum[r], off);
#pragma unroll
        for (int r = 0; r < 4; r++)
            l_run[r] = l_run[r] * alpha[r] + rsum[r];
#pragma unroll
        for (int ni = 0; ni < 4; ni++)
#pragma unroll
            for (int r = 0; r < 4; r++)
                oacc[ni][r] *= alpha[r];

        // O += P @ V   (P via LDS round-trip into A-layout; Vts is B-layout)
        bf16x8 pf0 = *(const bf16x8*)(&Ps[wave][lr * ASTR + quad * 8]);
        bf16x8 pf1 = *(const bf16x8*)(&Ps[wave][lr * ASTR + 32 + quad * 8]);
#pragma unroll
        for (int ni = 0; ni < 4; ni++) {
            bf16x8 vf0 = *(const bf16x8*)(&Vts[(ni * 16 + lr) * ASTR + quad * 8]);
            bf16x8 vf1 = *(const bf16x8*)(&Vts[(ni * 16 + lr) * ASTR + 32 + quad * 8]);
            oacc[ni] = __builtin_amdgcn_mfma_f32_16x16x32_bf16(pf0, vf0, oacc[ni], 0, 0, 0);
            oacc[ni] = __builtin_amdgcn_mfma_f32_16x16x32_bf16(pf1, vf1, oacc[ni], 0, 0, 0);
        }
    }

    // normalize + write o[b, q, h*64 + hd] as bf16
#pragma unroll
    for (int r = 0; r < 4; r++) {
        float inv = 1.0f / l_run[r];
        int gq = qt * 64 + wq + quad * 4 + r;
#pragma unroll
        for (int ni = 0; ni < 4; ni++)
            o[((size_t)(b * T_ + gq)) * H_ + h * 64 + ni * 16 + lr] =
                (bf16)(oacc[ni][r] * inv);
    }
}

// ---------------------------------------------------------------------------
extern "C" void kernel_launch(void* const* d_in, const int* in_sizes, int n_in,
                              void* d_out, int out_size, void* d_ws, size_t ws_size,
                              hipStream_t stream)
{
    const float* x_in  = (const float*)d_in[0];
    const float* ln1_g = (const float*)d_in[1];
    const float* ln1_b = (const float*)d_in[2];
    const float* f1w1  = (const float*)d_in[3];
    const float* f1b1  = (const float*)d_in[4];
    const float* f1w2  = (const float*)d_in[5];
    const float* f1b2  = (const float*)d_in[6];
    const float* an_g  = (const float*)d_in[7];
    const float* an_b  = (const float*)d_in[8];
    const float* qkv_w = (const float*)d_in[9];
    const float* qkv_b = (const float*)d_in[10];
    const float* out_w = (const float*)d_in[11];
    const float* out_b = (const float*)d_in[12];
    const float* cn_g  = (const float*)d_in[13];
    const float* cn_b  = (const float*)d_in[14];
    const float* dw_k  = (const float*)d_in[15];
    const float* dw_b  = (const float*)d_in[16];
    const float* pw_w  = (const float*)d_in[17];
    const float* pw_b  = (const float*)d_in[18];
    const float* ln2_g = (const float*)d_in[19];
    const float* ln2_b = (const float*)d_in[20];
    const float* f2w1  = (const float*)d_in[21];
    const float* f2b1  = (const float*)d_in[22];
    const float* f2w2  = (const float*)d_in[23];
    const float* f2b2  = (const float*)d_in[24];
    float* outp = (float*)d_out;

    char* ws = (char*)d_ws;
    size_t off = 0;
    auto alloc = [&](size_t bytes) {
        char* p = ws + off;
        off += (bytes + 255) & ~(size_t)255;
        return p;
    };
    bf16* w1T_1 = (bf16*)alloc(2048ULL * 1024 * 2);
    bf16* w2T_1 = (bf16*)alloc(1024ULL * 2048 * 2);
    bf16* qkvT  = (bf16*)alloc(3072ULL * 1024 * 2);
    bf16* outT  = (bf16*)alloc(1024ULL * 1024 * 2);
    bf16* pwB   = (bf16*)alloc(1024ULL * 1024 * 2);
    bf16* w1T_2 = (bf16*)alloc(2048ULL * 1024 * 2);
    bf16* w2T_2 = (bf16*)alloc(1024ULL * 2048 * 2);
    bf16* bufa  = (bf16*)alloc((size_t)MTOK * 1024 * 2);   // LN outs / attn out
    bf16* gbuf  = (bf16*)alloc((size_t)MTOK * 1024 * 2);   // conv-gelu out / vt alias
    bf16* hid   = (bf16*)alloc((size_t)MTOK * 3072 * 2);   // ffn hidden / qkv
    float* xw   = (float*)alloc((size_t)MTOK * 1024 * 4);  // running residual x
    bf16* vt    = gbuf;   // time-disjoint alias: vt live only during attention

    // ---- weight prep (bf16, B pre-transposed to [n][k]) ----
    transpose_cast_k<<<dim3(64, 32), 256, 0, stream>>>(f1w1, w1T_1, 1024, 2048);
    transpose_cast_k<<<dim3(32, 64), 256, 0, stream>>>(f1w2, w2T_1, 2048, 1024);
    transpose_cast_k<<<dim3(96, 32), 256, 0, stream>>>(qkv_w, qkvT, 1024, 3072);
    transpose_cast_k<<<dim3(32, 32), 256, 0, stream>>>(out_w, outT, 1024, 1024);
    transpose_cast_k<<<dim3(64, 32), 256, 0, stream>>>(f2w1, w1T_2, 1024, 2048);
    transpose_cast_k<<<dim3(32, 64), 256, 0, stream>>>(f2w2, w2T_2, 2048, 1024);
    cast_k<<<1024, 256, 0, stream>>>(pw_w, pwB);

    // ---- FFN1 (x += 0.5 * ffn(ln1(x))) ----
    ln_k<<<MTOK, 256, 0, stream>>>(x_in, ln1_g, ln1_b, bufa);
    gemm_k<0><<<dim3(64, 16), 256, 0, stream>>>(bufa, w1T_1, f1b1, nullptr, nullptr, hid, 2048, 1024);
    gemm_k<3><<<dim3(64, 8), 256, 0, stream>>>(hid, w2T_1, f1b2, x_in, xw, nullptr, 1024, 2048);

    // ---- attention ----
    ln_k<<<MTOK, 256, 0, stream>>>(xw, an_g, an_b, bufa);
    gemm_k<1><<<dim3(64, 24), 256, 0, stream>>>(bufa, qkvT, qkv_b, nullptr, nullptr, hid, 3072, 1024);
    transpose_v_k<<<dim3(16, 128), 256, 0, stream>>>(hid, vt);
    attn_k<<<dim3(16, 128), 256, 0, stream>>>(hid, vt, bufa);
    gemm_k<2><<<dim3(64, 8), 256, 0, stream>>>(bufa, outT, out_b, xw, xw, nullptr, 1024, 1024);

    // ---- conv module ----
    ln_k<<<MTOK, 256, 0, stream>>>(xw, cn_g, cn_b, bufa);
    dwconv_k<<<MTOK * 1024 / 256, 256, 0, stream>>>(bufa, dw_k, dw_b, gbuf);
    gemm_k<2><<<dim3(64, 8), 256, 0, stream>>>(gbuf, pwB, pw_b, xw, xw, nullptr, 1024, 1024);

    // ---- FFN2 ----
    ln_k<<<MTOK, 256, 0, stream>>>(xw, ln2_g, ln2_b, bufa);
    gemm_k<0><<<dim3(64, 16), 256, 0, stream>>>(bufa, w1T_2, f2b1, nullptr, nullptr, hid, 2048, 1024);
    gemm_k<3><<<dim3(64, 8), 256, 0, stream>>>(hid, w2T_2, f2b2, xw, outp, nullptr, 1024, 2048);
}